// Round 11
// baseline (182.423 us; speedup 1.0000x reference)
//
#include <hip/hip_runtime.h>
#include <math.h>

#define DM 256   // d_model
#define NP 256   // n == m == 256 points
#define NH 4     // heads
#define DH 64    // dim per head
#define NBLK 256 // grid size (1 block per CU; co-resident by capacity)

typedef unsigned long long u64;
typedef unsigned int u32;

union SMem {
  struct { float Ws[2][32][64]; float Xs[2][32][64]; } p1;            // 32 KB
  struct { float Qs[64][68]; float Ks[64][68]; } p2;                  // 34 KB
  struct { float eslot[4][64]; int msel[4][64];
           float4 ang[4][64]; float otile[4][64]; } p3;               // 7 KB
  struct { float Wc[2][32][32]; float Xc[2][32][32]; } p4;            // 16 KB
};

// Software grid barrier: all NBLK blocks are co-resident (grid == #CUs,
// 1 block/CU capacity), so spin-wait cannot deadlock. Counters are zeroed
// by a hipMemsetAsync node before each launch (deterministic across graph
// replays). Release fence before arrive, acquire after; trailing fence on
// all threads for cross-XCD L2 visibility.
__device__ __forceinline__ void grid_barrier(int* bar, int idx) {
  __syncthreads();
  if (threadIdx.x == 0) {
    __threadfence();
    atomicAdd(&bar[idx], 1);
    while (__hip_atomic_load(&bar[idx], __ATOMIC_ACQUIRE,
                             __HIP_MEMORY_SCOPE_AGENT) < NBLK) { }
  }
  __syncthreads();
  __threadfence();
}

// ---------------------------------------------------------------------------
// One persistent kernel, 256 blocks x 256 threads:
//  P1 qkv projections -> Qt/Kt/Vt   (192 units, R7-proven body)
//  P2 score GEMM      -> scores     (256 units, R7-proven body)
//  P3 ballot top-k + rotary gather -> O (4 sweeps x 256, R9-proven body)
//  P4 final projection -> out       (256 units of 32x32, full-CU spread)
// O aliases Qt (Qt dead after P2; enforced by barrier).
// ---------------------------------------------------------------------------
__global__ __launch_bounds__(256, 1) void mega_kernel(
    const float* __restrict__ x, const float* __restrict__ src,
    const float* __restrict__ Wq, const float* __restrict__ bq,
    const float* __restrict__ Wk, const float* __restrict__ bk,
    const float* __restrict__ Wv, const float* __restrict__ bv,
    const float* __restrict__ Wm, const float* __restrict__ bm,
    const float* __restrict__ x_pos, const float* __restrict__ src_pos,
    const float* __restrict__ lrf, const int* __restrict__ kptr,
    float* __restrict__ Qt, float* __restrict__ Kt, float* __restrict__ Vt,
    float* __restrict__ scores, float* __restrict__ O,
    int* __restrict__ bar,
    float* __restrict__ out)
{
  __shared__ SMem S;
  const int tid = threadIdx.x;
  const int bid = blockIdx.x;

  // ======================= P1: Q/K/V projection ===========================
  if (bid < 192) {
    const int tile = bid & 15;        // 4x4 grid of 64x64 tiles
    const int r    = bid >> 4;        // 0..11
    const int mat  = r % 3;           // 0=q,1=k,2=v
    const int b    = r / 3;
    const int tc = (tile >> 2) * 64;
    const int tp = (tile & 3) * 64;
    const float* W    = (mat == 0) ? Wq : (mat == 1) ? Wk : Wv;
    const float* bias = (mat == 0) ? bq : (mat == 1) ? bk : bv;
    const float* X    = ((mat == 0) ? x : src) + (size_t)b * DM * NP;
    float* T          = ((mat == 0) ? Qt : (mat == 1) ? Kt : Vt)
                        + (size_t)b * NH * NP * DH;

    const int ty = tid >> 4, tx = tid & 15;
    const int c0 = tid >> 3;
    const int k4 = tid & 7;
    const int pX = tid & 15;
    const int kX = tid >> 4;

    float4 wA, wB, xA, xB;
    #define LOADQKV(K0)                                                        \
      wA = *(const float4*)&W[(size_t)(tc + c0)      * DM + (K0) + k4 * 4];    \
      wB = *(const float4*)&W[(size_t)(tc + c0 + 32) * DM + (K0) + k4 * 4];    \
      xA = *(const float4*)&X[(size_t)((K0) + kX)      * NP + tp + pX * 4];    \
      xB = *(const float4*)&X[(size_t)((K0) + kX + 16) * NP + tp + pX * 4];
    #define STOREQKV(BUF)                                                      \
      S.p1.Ws[BUF][k4*4+0][c0] = wA.x; S.p1.Ws[BUF][k4*4+1][c0] = wA.y;        \
      S.p1.Ws[BUF][k4*4+2][c0] = wA.z; S.p1.Ws[BUF][k4*4+3][c0] = wA.w;        \
      S.p1.Ws[BUF][k4*4+0][c0+32] = wB.x; S.p1.Ws[BUF][k4*4+1][c0+32] = wB.y;  \
      S.p1.Ws[BUF][k4*4+2][c0+32] = wB.z; S.p1.Ws[BUF][k4*4+3][c0+32] = wB.w;  \
      *(float4*)&S.p1.Xs[BUF][kX][pX*4]    = xA;                               \
      *(float4*)&S.p1.Xs[BUF][kX+16][pX*4] = xB;

    LOADQKV(0);
    STOREQKV(0);
    __syncthreads();

    float acc[4][4];
    #pragma unroll
    for (int i = 0; i < 4; ++i)
      #pragma unroll
      for (int j = 0; j < 4; ++j) acc[i][j] = 0.f;

    for (int ch = 0; ch < 8; ++ch) {
      const int cur = ch & 1;
      if (ch < 7) { LOADQKV((ch + 1) * 32); }
      #pragma unroll
      for (int kx = 0; kx < 32; ++kx) {
        float4 a  = *(const float4*)&S.p1.Ws[cur][kx][ty * 4];
        float4 xv = *(const float4*)&S.p1.Xs[cur][kx][tx * 4];
        float av[4]  = {a.x, a.y, a.z, a.w};
        float xvv[4] = {xv.x, xv.y, xv.z, xv.w};
        #pragma unroll
        for (int i = 0; i < 4; ++i)
          #pragma unroll
          for (int j = 0; j < 4; ++j) acc[i][j] += av[i] * xvv[j];
      }
      if (ch < 7) {
        STOREQKV(cur ^ 1);
        __syncthreads();
      }
    }

    #pragma unroll
    for (int i = 0; i < 4; ++i) {
      const int c = tc + ty * 4 + i;
      const float bb = bias[c];
      #pragma unroll
      for (int j = 0; j < 4; ++j) {
        const int p = tp + tx * 4 + j;
        T[((size_t)(c & 3) * NP + p) * DH + (c >> 2)] = acc[i][j] + bb;
      }
    }
    #undef LOADQKV
    #undef STOREQKV
  }

  grid_barrier(bar, 0);

  // ======================= P2: score GEMM =================================
  {
    const int tile = bid & 15;
    const int bh   = bid >> 4;
    const int tn = (tile >> 2) * 64;
    const int tm = (tile & 3) * 64;
    const float* Qb = Qt + (size_t)bh * NP * DH;
    const float* Kb = Kt + (size_t)bh * NP * DH;

    #pragma unroll
    for (int p = 0; p < 4; ++p) {
      const int u = tid + p * 256;
      const int r = u >> 4;
      const int g = u & 15;
      const float4 qv = *(const float4*)&Qb[(size_t)(tn + r) * DH + g * 4];
      const float4 kv = *(const float4*)&Kb[(size_t)(tm + r) * DH + g * 4];
      S.p2.Qs[g*4+0][r] = qv.x; S.p2.Qs[g*4+1][r] = qv.y;
      S.p2.Qs[g*4+2][r] = qv.z; S.p2.Qs[g*4+3][r] = qv.w;
      S.p2.Ks[g*4+0][r] = kv.x; S.p2.Ks[g*4+1][r] = kv.y;
      S.p2.Ks[g*4+2][r] = kv.z; S.p2.Ks[g*4+3][r] = kv.w;
    }
    __syncthreads();

    const int ty = tid >> 4, tx = tid & 15;
    float acc[4][4];
    #pragma unroll
    for (int i = 0; i < 4; ++i)
      #pragma unroll
      for (int j = 0; j < 4; ++j) acc[i][j] = 0.f;

    #pragma unroll 4
    for (int d = 0; d < DH; ++d) {
      const float4 a  = *(const float4*)&S.p2.Qs[d][ty * 4];
      const float4 bv = *(const float4*)&S.p2.Ks[d][tx * 4];
      const float av[4]  = {a.x, a.y, a.z, a.w};
      const float bvv[4] = {bv.x, bv.y, bv.z, bv.w};
      #pragma unroll
      for (int i = 0; i < 4; ++i)
        #pragma unroll
        for (int j = 0; j < 4; ++j) acc[i][j] += av[i] * bvv[j];
    }

    float* srow = scores + ((size_t)bh * NP + tn) * NP + tm;
    #pragma unroll
    for (int i = 0; i < 4; ++i) {
      float4 o4;
      o4.x = acc[i][0] * 0.125f; o4.y = acc[i][1] * 0.125f;
      o4.z = acc[i][2] * 0.125f; o4.w = acc[i][3] * 0.125f;
      *(float4*)&srow[(size_t)(ty * 4 + i) * NP + tx * 4] = o4;
    }
  }

  grid_barrier(bar, 1);

  // ======================= P3: ballot top-k + gather ======================
  {
    const int wid  = tid >> 6;
    const int lane = tid & 63;
    int kk = *kptr;
    if (kk > 64) kk = 64;
    if (kk < 1) kk = 1;

    for (int sweep = 0; sweep < 4; ++sweep) {
      const int rb  = sweep * 256 + bid;        // 0..1023
      const int row = rb * 4 + wid;             // bh*256 + n
      const int n   = row & (NP - 1);
      const int bh  = row >> 8;
      const int b   = bh >> 2;
      const int h   = bh & 3;

      const float4 s4 = *(const float4*)&scores[(size_t)row * NP + lane * 4];
      float s[4] = { s4.x, s4.y, s4.z, s4.w };
      u32 u[4], lowv[4];
      #pragma unroll
      for (int r = 0; r < 4; ++r) {
        u32 bb = __float_as_uint(s[r]);
        u[r] = (bb & 0x80000000u) ? ~bb : (bb | 0x80000000u);
        lowv[r] = (u32)(255 - (lane * 4 + r));
      }

      // phase 1: T = value-bits of kth largest
      u32 T = 0u;
      #pragma unroll
      for (int bit = 31; bit >= 0; --bit) {
        const u32 cand = T | (1u << bit);
        int c = 0;
        #pragma unroll
        for (int r = 0; r < 4; ++r) c += __popcll(__ballot(u[r] >= cand));
        if (c >= kk) T = cand;
      }
      int c_gt = 0, c_ge = 0;
      #pragma unroll
      for (int r = 0; r < 4; ++r) {
        c_gt += __popcll(__ballot(u[r] > T));
        c_ge += __popcll(__ballot(u[r] >= T));
      }

      // phase 2 (ties only): threshold on low bits (255-m)
      u32 Lo = 0u;
      if (c_ge > kk) {
        #pragma unroll
        for (int bit = 7; bit >= 0; --bit) {
          const u32 cand = Lo | (1u << bit);
          int c = c_gt;
          #pragma unroll
          for (int r = 0; r < 4; ++r)
            c += __popcll(__ballot((u[r] == T) && (lowv[r] >= cand)));
          if (c >= kk) Lo = cand;
        }
      }

      // membership (exactly kk), e-values, Z
      const float sT = __uint_as_float((T & 0x80000000u) ? (T & 0x7fffffffu) : ~T);
      bool sel[4]; float e[4]; u64 selm[4];
      #pragma unroll
      for (int r = 0; r < 4; ++r) {
        sel[r] = (u[r] > T) || ((u[r] == T) && (lowv[r] >= Lo));
        e[r] = sel[r] ? expf(s[r] - sT) : 0.f;
        selm[r] = __ballot(sel[r]);
      }
      float z = e[0] + e[1] + e[2] + e[3];
      #pragma unroll
      for (int off = 32; off; off >>= 1) z += __shfl_xor(z, off);

      // compaction: slot by (r-major, lane) order
      const u64 lt = (1ull << lane) - 1ull;
      int base = 0;
      #pragma unroll
      for (int r = 0; r < 4; ++r) {
        if (sel[r]) {
          const int slot = base + __popcll(selm[r] & lt);
          S.p3.eslot[wid][slot] = e[r];
          S.p3.msel[wid][slot]  = lane * 4 + r;
        }
        base += __popcll(selm[r]);
      }

      // lane j: rotary-angle coefficients for slot j (algebraic)
      if (lane < kk) {
        const float ej = S.p3.eslot[wid][lane];
        const int   mj = S.p3.msel[wid][lane];
        const float p = ej / z;
        const float* xp = x_pos   + ((size_t)b * NP + mj) * 3;
        const float* sp = src_pos + ((size_t)b * NP + n) * 3;
        const float* L  = lrf     + ((size_t)b * NP + mj) * 9;
        const float r0 = xp[0] - sp[0], r1 = xp[1] - sp[1], r2v = xp[2] - sp[2];
        const float px = L[0]*r0 + L[3]*r1 + L[6]*r2v;   // lrf^T r
        const float py = L[1]*r0 + L[4]*r1 + L[7]*r2v;
        const float pz = L[2]*r0 + L[5]*r1 + L[8]*r2v;
        const float r2 = px*px + py*py;
        const float inv2 = (r2 > 0.f) ? rsqrtf(r2) : 0.f;
        const float ca = (r2 > 0.f) ? px * inv2 : 1.f;
        const float sa = py * inv2;
        const float r2d = r2 * inv2;
        const float r3 = r2 + pz * pz;
        const float inv3 = (r3 > 0.f) ? rsqrtf(r3) : 0.f;
        const float cph = (r3 > 0.f) ? r2d * inv3 : 1.f;
        const float sph = pz * inv3;
        S.p3.ang[wid][lane] = make_float4(p * ca, p * sa, p * cph, p * sph);
      }

      // gather: LDS-broadcast coefs + coalesced V float2 loads
      const float* vbase = Vt + (size_t)bh * NP * DH;
      const bool useA = ((lane & 3) < 2);
      const bool odd  = (lane & 1);
      const int  ev   = lane & ~1;
      float acc = 0.f;

      int j = 0;
      for (; j + 4 <= kk; j += 4) {
        const int ma = S.p3.msel[wid][j],   mb2 = S.p3.msel[wid][j+1];
        const int mc = S.p3.msel[wid][j+2], md = S.p3.msel[wid][j+3];
        const float4 Aa = S.p3.ang[wid][j],   Ab = S.p3.ang[wid][j+1];
        const float4 Ac = S.p3.ang[wid][j+2], Ad = S.p3.ang[wid][j+3];
        const float2 va = *(const float2*)(vbase + (size_t)ma  * DH + ev);
        const float2 vb = *(const float2*)(vbase + (size_t)mb2 * DH + ev);
        const float2 vc = *(const float2*)(vbase + (size_t)mc  * DH + ev);
        const float2 vd = *(const float2*)(vbase + (size_t)md  * DH + ev);
        float vm, dsc, pc, ps;
        vm = odd ? va.y : va.x;  dsc = odd ? va.x : -va.y;
        pc = useA ? Aa.x : Aa.z; ps  = useA ? Aa.y : Aa.w;
        acc += vm * pc + dsc * ps;
        vm = odd ? vb.y : vb.x;  dsc = odd ? vb.x : -vb.y;
        pc = useA ? Ab.x : Ab.z; ps  = useA ? Ab.y : Ab.w;
        acc += vm * pc + dsc * ps;
        vm = odd ? vc.y : vc.x;  dsc = odd ? vc.x : -vc.y;
        pc = useA ? Ac.x : Ac.z; ps  = useA ? Ac.y : Ac.w;
        acc += vm * pc + dsc * ps;
        vm = odd ? vd.y : vd.x;  dsc = odd ? vd.x : -vd.y;
        pc = useA ? Ad.x : Ad.z; ps  = useA ? Ad.y : Ad.w;
        acc += vm * pc + dsc * ps;
      }
      for (; j < kk; ++j) {
        const int m = S.p3.msel[wid][j];
        const float4 A = S.p3.ang[wid][j];
        const float2 v2 = *(const float2*)(vbase + (size_t)m * DH + ev);
        const float vm  = odd ? v2.y :  v2.x;
        const float dsc = odd ? v2.x : -v2.y;
        acc += vm * (useA ? A.x : A.z) + dsc * (useA ? A.y : A.w);
      }

      S.p3.otile[wid][lane] = acc;
      __syncthreads();
      if (wid == 0) {
        float4 o4;
        o4.x = S.p3.otile[0][lane]; o4.y = S.p3.otile[1][lane];
        o4.z = S.p3.otile[2][lane]; o4.w = S.p3.otile[3][lane];
        const int c = (lane << 2) | h;
        const int n0 = (rb * 4) & (NP - 1);
        *(float4*)&O[((size_t)b * DM + c) * NP + n0] = o4;
      }
      __syncthreads();   // protect otile before next sweep rewrites it
    }
  }

  grid_barrier(bar, 2);

  // ======================= P4: final projection (32x32 tiles) =============
  {
    const int tp = (bid & 7) * 32;
    const int tc = ((bid >> 3) & 7) * 32;
    const int b  = bid >> 6;
    const float* X = O + (size_t)b * DM * NP;
    float* Y       = out + (size_t)b * DM * NP;

    const int c0w = tid >> 3, kg = tid & 7;   // W staging: 32c x 8 f4-groups
    const int krx = tid >> 3, pg = tid & 7;   // X staging: 32k x 8 f4-groups
    const int ty = tid >> 4, tx = tid & 15;

    float4 wv4, xv4;
    #define LOADP4(K0)                                                         \
      wv4 = *(const float4*)&Wm[(size_t)(tc + c0w) * DM + (K0) + kg * 4];      \
      xv4 = *(const float4*)&X[(size_t)((K0) + krx) * NP + tp + pg * 4];
    #define STOREP4(BUF)                                                       \
      S.p4.Wc[BUF][kg*4+0][c0w] = wv4.x; S.p4.Wc[BUF][kg*4+1][c0w] = wv4.y;    \
      S.p4.Wc[BUF][kg*4+2][c0w] = wv4.z; S.p4.Wc[BUF][kg*4+3][c0w] = wv4.w;    \
      *(float4*)&S.p4.Xc[BUF][krx][pg*4] = xv4;

    LOADP4(0);
    STOREP4(0);
    __syncthreads();

    float a00 = 0.f, a01 = 0.f, a10 = 0.f, a11 = 0.f;
    for (int ch = 0; ch < 8; ++ch) {
      const int cur = ch & 1;
      if (ch < 7) { LOADP4((ch + 1) * 32); }
      #pragma unroll
      for (int kx = 0; kx < 32; ++kx) {
        const float2 wv = *(const float2*)&S.p4.Wc[cur][kx][ty * 2];
        const float2 xv = *(const float2*)&S.p4.Xc[cur][kx][tx * 2];
        a00 += wv.x * xv.x; a01 += wv.x * xv.y;
        a10 += wv.y * xv.x; a11 += wv.y * xv.y;
      }
      if (ch < 7) {
        STOREP4(cur ^ 1);
        __syncthreads();
      }
    }

    const int c = tc + ty * 2;
    const int p = tp + tx * 2;
    const float b0 = bm[c], b1 = bm[c + 1];
    float2 o0 = make_float2(a00 + b0, a01 + b0);
    float2 o1 = make_float2(a10 + b1, a11 + b1);
    *(float2*)&Y[(size_t)c       * NP + p] = o0;
    *(float2*)&Y[(size_t)(c + 1) * NP + p] = o1;
    #undef LOADP4
    #undef STOREP4
  }
}

// ---------------------------------------------------------------------------
extern "C" void kernel_launch(void* const* d_in, const int* in_sizes, int n_in,
                              void* d_out, int out_size, void* d_ws, size_t ws_size,
                              hipStream_t stream)
{
  const float* x       = (const float*)d_in[0];
  const float* source  = (const float*)d_in[1];
  const float* x_pos   = (const float*)d_in[2];
  const float* src_pos = (const float*)d_in[3];
  const float* lrf     = (const float*)d_in[4];
  const float* Wq = (const float*)d_in[5];
  const float* bq = (const float*)d_in[6];
  const float* Wk = (const float*)d_in[7];
  const float* bk = (const float*)d_in[8];
  const float* Wv = (const float*)d_in[9];
  const float* bv = (const float*)d_in[10];
  const float* Wm = (const float*)d_in[11];
  const float* bm = (const float*)d_in[12];
  const int* kptr = (const int*)d_in[13];
  float* out = (float*)d_out;

  // workspace layout (floats): Qt (aliased as O after P2), Kt, Vt, scores,
  // then 64B of grid-barrier counters. Total 7 MB + 64 B.
  float* ws = (float*)d_ws;
  float* Qt = ws;                         // [16][256][64]  = 262144 (also O)
  float* Kt = Qt + 262144;
  float* Vt = Kt + 262144;
  float* scores = Vt + 262144;            // [16][256][256] = 1048576
  int*   bar = (int*)(scores + 1048576);  // 16 ints
  float* O  = Qt;                         // alias: Qt dead after P2

  hipMemsetAsync(bar, 0, 64, stream);
  mega_kernel<<<dim3(NBLK), 256, 0, stream>>>(
      x, source, Wq, bq, Wk, bk, Wv, bv, Wm, bm,
      x_pos, src_pos, lrf, kptr,
      Qt, Kt, Vt, scores, O, bar, out);
}

// Round 12
// 43.571 us; speedup vs baseline: 4.1868x; 4.1868x over previous
//
#include <hip/hip_runtime.h>
#include <math.h>

#define DM 256   // d_model
#define NP 256   // n == m == 256 points
#define NH 4     // heads
#define DH 64    // dim per head

typedef unsigned long long u64;
typedef unsigned int u32;

// ---------------------------------------------------------------------------
// Kernel 1: qkv partial GEMM, split-K x2. 384 blocks. No bias/transpose here:
// outputs P[ks][mat][b][c][p] row-major [c][p]; consumers fold sum+bias.
// ---------------------------------------------------------------------------
__global__ __launch_bounds__(256) void qkv_part_kernel(
    const float* __restrict__ x, const float* __restrict__ src,
    const float* __restrict__ Wq, const float* __restrict__ Wk,
    const float* __restrict__ Wv,
    float* __restrict__ Ppart)
{
  const int tile = blockIdx.x;      // 16: 4x4 of 64x64 tiles
  const int mat  = blockIdx.y;      // 0=q,1=k,2=v
  const int bz   = blockIdx.z;      // b*2 + ks
  const int b  = bz >> 1;
  const int ks = bz & 1;
  const int tc = (tile >> 2) * 64;
  const int tp = (tile & 3) * 64;
  const float* W = (mat == 0) ? Wq : (mat == 1) ? Wk : Wv;
  const float* X = ((mat == 0) ? x : src) + (size_t)b * DM * NP;
  float* P = Ppart + ((size_t)((ks * 3 + mat) * 4 + b)) * 65536;

  __shared__ float Ws[2][32][64];
  __shared__ float Xs[2][32][64];
  const int tid = threadIdx.x;
  const int ty = tid >> 4, tx = tid & 15;
  const int c0 = tid >> 3;
  const int k4 = tid & 7;
  const int pX = tid & 15;
  const int kX = tid >> 4;
  const int kbase = ks * 128;

  float4 wA, wB, xA, xB;
  #define LOADQKV(K0)                                                          \
    wA = *(const float4*)&W[(size_t)(tc + c0)      * DM + (K0) + k4 * 4];      \
    wB = *(const float4*)&W[(size_t)(tc + c0 + 32) * DM + (K0) + k4 * 4];      \
    xA = *(const float4*)&X[(size_t)((K0) + kX)      * NP + tp + pX * 4];      \
    xB = *(const float4*)&X[(size_t)((K0) + kX + 16) * NP + tp + pX * 4];

  #define STOREQKV(BUF)                                                        \
    Ws[BUF][k4*4+0][c0] = wA.x; Ws[BUF][k4*4+1][c0] = wA.y;                    \
    Ws[BUF][k4*4+2][c0] = wA.z; Ws[BUF][k4*4+3][c0] = wA.w;                    \
    Ws[BUF][k4*4+0][c0+32] = wB.x; Ws[BUF][k4*4+1][c0+32] = wB.y;              \
    Ws[BUF][k4*4+2][c0+32] = wB.z; Ws[BUF][k4*4+3][c0+32] = wB.w;              \
    *(float4*)&Xs[BUF][kX][pX*4]      = xA;                                    \
    *(float4*)&Xs[BUF][kX+16][pX*4]   = xB;

  LOADQKV(kbase);
  STOREQKV(0);
  __syncthreads();

  float acc[4][4];
  #pragma unroll
  for (int i = 0; i < 4; ++i)
    #pragma unroll
    for (int j = 0; j < 4; ++j) acc[i][j] = 0.f;

  for (int ch = 0; ch < 4; ++ch) {          // K = 128 per block
    const int cur = ch & 1;
    if (ch < 3) { LOADQKV(kbase + (ch + 1) * 32); }
    #pragma unroll
    for (int kk = 0; kk < 32; ++kk) {
      float4 a = *(const float4*)&Ws[cur][kk][ty * 4];
      float4 xv = *(const float4*)&Xs[cur][kk][tx * 4];
      float av[4] = {a.x, a.y, a.z, a.w};
      float xvv[4] = {xv.x, xv.y, xv.z, xv.w};
      #pragma unroll
      for (int i = 0; i < 4; ++i)
        #pragma unroll
        for (int j = 0; j < 4; ++j) acc[i][j] += av[i] * xvv[j];
    }
    if (ch < 3) {
      STOREQKV(cur ^ 1);
      __syncthreads();
    }
  }

  #pragma unroll
  for (int i = 0; i < 4; ++i) {
    float4 o4;
    o4.x = acc[i][0]; o4.y = acc[i][1]; o4.z = acc[i][2]; o4.w = acc[i][3];
    *(float4*)&P[(size_t)(tc + ty * 4 + i) * NP + tp + tx * 4] = o4;
  }
  #undef LOADQKV
  #undef STOREQKV
}

// ---------------------------------------------------------------------------
// Kernel 2: score GEMM; stages Q,K from split-K partials (sum + bias folded),
// proven GEMM body; also merges this tile's 16 V rows -> Vt (sum+bias,
// transposed through LDS, coalesced out).
// ---------------------------------------------------------------------------
__global__ __launch_bounds__(256) void score_gemm_kernel(
    const float* __restrict__ Ppart,
    const float* __restrict__ bq, const float* __restrict__ bk,
    const float* __restrict__ bv,
    float* __restrict__ scores, float* __restrict__ Vt)
{
  const int tile = blockIdx.x;          // 16 = 4x4 tiles of 64x64
  const int bh   = blockIdx.y;          // 16
  const int tn = (tile >> 2) * 64;
  const int tm = (tile & 3) * 64;
  const int b = bh >> 2, h = bh & 3;

  const float* PQ0 = Ppart + ((size_t)( 0 + b)) * 65536;  // ks0 mat0
  const float* PQ1 = Ppart + ((size_t)(12 + b)) * 65536;  // ks1 mat0
  const float* PK0 = Ppart + ((size_t)( 4 + b)) * 65536;  // ks0 mat1
  const float* PK1 = Ppart + ((size_t)(16 + b)) * 65536;  // ks1 mat1
  const float* PV0 = Ppart + ((size_t)( 8 + b)) * 65536;  // ks0 mat2
  const float* PV1 = Ppart + ((size_t)(20 + b)) * 65536;  // ks1 mat2

  __shared__ float Qs[64][68];   // [d][n]
  __shared__ float Ks[64][68];   // [d][m]
  __shared__ float Vs[16][68];   // V-merge transpose tile [m][d]
  const int tid = threadIdx.x;

  // ---- staging: Qs/Ks from partial sums + bias -----------------------------
  #pragma unroll
  for (int pass = 0; pass < 4; ++pass) {
    const int u  = tid + pass * 256;     // 0..1023
    const int pg = u & 15;               // point 4-group
    const int d  = u >> 4;               // 0..63
    const int c  = d * 4 + h;
    const float bqv = bq[c], bkv = bk[c];
    const float4 q0 = *(const float4*)&PQ0[(size_t)c * NP + tn + pg * 4];
    const float4 q1 = *(const float4*)&PQ1[(size_t)c * NP + tn + pg * 4];
    const float4 k0 = *(const float4*)&PK0[(size_t)c * NP + tm + pg * 4];
    const float4 k1 = *(const float4*)&PK1[(size_t)c * NP + tm + pg * 4];
    Qs[d][pg*4+0] = q0.x + q1.x + bqv;
    Qs[d][pg*4+1] = q0.y + q1.y + bqv;
    Qs[d][pg*4+2] = q0.z + q1.z + bqv;
    Qs[d][pg*4+3] = q0.w + q1.w + bqv;
    Ks[d][pg*4+0] = k0.x + k1.x + bkv;
    Ks[d][pg*4+1] = k0.y + k1.y + bkv;
    Ks[d][pg*4+2] = k0.z + k1.z + bkv;
    Ks[d][pg*4+3] = k0.w + k1.w + bkv;
  }
  __syncthreads();

  const int ty = tid >> 4, tx = tid & 15;
  float acc[4][4];
  #pragma unroll
  for (int i = 0; i < 4; ++i)
    #pragma unroll
    for (int j = 0; j < 4; ++j) acc[i][j] = 0.f;

  #pragma unroll 4
  for (int d = 0; d < DH; ++d) {
    const float4 a  = *(const float4*)&Qs[d][ty * 4];
    const float4 bvv4 = *(const float4*)&Ks[d][tx * 4];
    const float av[4]  = {a.x, a.y, a.z, a.w};
    const float bvv[4] = {bvv4.x, bvv4.y, bvv4.z, bvv4.w};
    #pragma unroll
    for (int i = 0; i < 4; ++i)
      #pragma unroll
      for (int j = 0; j < 4; ++j) acc[i][j] += av[i] * bvv[j];
  }

  float* srow = scores + ((size_t)bh * NP + tn) * NP + tm;
  #pragma unroll
  for (int i = 0; i < 4; ++i) {
    float4 o4;
    o4.x = acc[i][0] * 0.125f; o4.y = acc[i][1] * 0.125f;
    o4.z = acc[i][2] * 0.125f; o4.w = acc[i][3] * 0.125f;
    *(float4*)&srow[(size_t)(ty * 4 + i) * NP + tx * 4] = o4;
  }

  // ---- V-merge side job: 16 m's (m = tile*16 .. +15) -----------------------
  {
    const int dV = tid >> 2;             // 0..63
    const int mg = tid & 3;              // 0..3  (m 4-group)
    const int cV = dV * 4 + h;
    const float bvb = bv[cV];
    const float4 v0 = *(const float4*)&PV0[(size_t)cV * NP + tile * 16 + mg * 4];
    const float4 v1 = *(const float4*)&PV1[(size_t)cV * NP + tile * 16 + mg * 4];
    Vs[mg*4+0][dV] = v0.x + v1.x + bvb;
    Vs[mg*4+1][dV] = v0.y + v1.y + bvb;
    Vs[mg*4+2][dV] = v0.z + v1.z + bvb;
    Vs[mg*4+3][dV] = v0.w + v1.w + bvb;
  }
  __syncthreads();
  {
    const int mrow = tid >> 4;           // 0..15
    const int dg   = tid & 15;           // 0..15
    const float4 o = *(const float4*)&Vs[mrow][dg * 4];
    *(float4*)&Vt[((size_t)bh * NP + tile * 16 + mrow) * DH + dg * 4] = o;
  }
}

// ---------------------------------------------------------------------------
// Kernel 3: ballot-radix top-k (R9-proven) + software-pipelined gather.
// ---------------------------------------------------------------------------
__global__ __launch_bounds__(256) void attn_topk_kernel(
    const float* __restrict__ scores, const float* __restrict__ Vt,
    const float* __restrict__ x_pos, const float* __restrict__ src_pos,
    const float* __restrict__ lrf,
    const int* __restrict__ kptr,
    float* __restrict__ O)
{
  const int tid  = threadIdx.x;
  const int wid  = tid >> 6;
  const int lane = tid & 63;
  const int bidx = blockIdx.x;                      // 0..1023
  const int rb   = (bidx & 7) * 128 + (bidx >> 3);  // bijective XCD swizzle
  const int row  = rb * 4 + wid;
  const int n    = row & (NP - 1);
  const int bh   = row >> 8;
  const int b    = bh >> 2;
  const int h    = bh & 3;

  int kk = *kptr;
  if (kk > 64) kk = 64;
  if (kk < 1) kk = 1;

  __shared__ float  eslot[4][64];
  __shared__ int    msel[4][64];
  __shared__ float4 ang[4][64];
  __shared__ float  otile[4][64];

  const float4 s4 = *(const float4*)&scores[(size_t)row * NP + lane * 4];
  float s[4] = { s4.x, s4.y, s4.z, s4.w };
  u32 u[4], lowv[4];
  #pragma unroll
  for (int r = 0; r < 4; ++r) {
    u32 bb = __float_as_uint(s[r]);
    u[r] = (bb & 0x80000000u) ? ~bb : (bb | 0x80000000u);
    lowv[r] = (u32)(255 - (lane * 4 + r));
  }

  // phase 1: T = value-bits of kth largest
  u32 T = 0u;
  #pragma unroll
  for (int bit = 31; bit >= 0; --bit) {
    const u32 cand = T | (1u << bit);
    int c = 0;
    #pragma unroll
    for (int r = 0; r < 4; ++r) c += __popcll(__ballot(u[r] >= cand));
    if (c >= kk) T = cand;
  }
  int c_gt = 0;
  #pragma unroll
  for (int r = 0; r < 4; ++r) c_gt += __popcll(__ballot(u[r] > T));

  // phase 2: tie-break threshold on low bits (255-m)
  u32 Lo = 0u;
  #pragma unroll
  for (int bit = 7; bit >= 0; --bit) {
    const u32 cand = Lo | (1u << bit);
    int c = c_gt;
    #pragma unroll
    for (int r = 0; r < 4; ++r)
      c += __popcll(__ballot((u[r] == T) && (lowv[r] >= cand)));
    if (c >= kk) Lo = cand;
  }

  // membership, e-values, Z
  const float sT = __uint_as_float((T & 0x80000000u) ? (T & 0x7fffffffu) : ~T);
  bool sel[4]; float e[4]; u64 selm[4];
  #pragma unroll
  for (int r = 0; r < 4; ++r) {
    sel[r] = (u[r] > T) || ((u[r] == T) && (lowv[r] >= Lo));
    e[r] = sel[r] ? expf(s[r] - sT) : 0.f;
    selm[r] = __ballot(sel[r]);
  }
  float z = e[0] + e[1] + e[2] + e[3];
  #pragma unroll
  for (int off = 32; off; off >>= 1) z += __shfl_xor(z, off);

  // compaction
  const u64 lt = (1ull << lane) - 1ull;
  int base = 0;
  #pragma unroll
  for (int r = 0; r < 4; ++r) {
    if (sel[r]) {
      const int slot = base + __popcll(selm[r] & lt);
      eslot[wid][slot] = e[r];
      msel[wid][slot]  = lane * 4 + r;
    }
    base += __popcll(selm[r]);
  }

  // lane j: rotary-angle coefficients for slot j (algebraic)
  if (lane < kk) {
    const float ej = eslot[wid][lane];
    const int   mj = msel[wid][lane];
    const float p = ej / z;
    const float* xp = x_pos   + ((size_t)b * NP + mj) * 3;
    const float* sp = src_pos + ((size_t)b * NP + n) * 3;
    const float* L  = lrf     + ((size_t)b * NP + mj) * 9;
    const float r0 = xp[0] - sp[0], r1 = xp[1] - sp[1], r2v = xp[2] - sp[2];
    const float px = L[0]*r0 + L[3]*r1 + L[6]*r2v;   // lrf^T r
    const float py = L[1]*r0 + L[4]*r1 + L[7]*r2v;
    const float pz = L[2]*r0 + L[5]*r1 + L[8]*r2v;
    const float r2 = px*px + py*py;
    const float inv2 = (r2 > 0.f) ? rsqrtf(r2) : 0.f;
    const float ca = (r2 > 0.f) ? px * inv2 : 1.f;
    const float sa = py * inv2;
    const float r2d = r2 * inv2;
    const float r3 = r2 + pz * pz;
    const float inv3 = (r3 > 0.f) ? rsqrtf(r3) : 0.f;
    const float cph = (r3 > 0.f) ? r2d * inv3 : 1.f;
    const float sph = pz * inv3;
    ang[wid][lane] = make_float4(p * ca, p * sa, p * cph, p * sph);
  }

  // gather: 2-stage software pipeline (prefetch next 4 V-float2s)
  const float* vbase = Vt + (size_t)bh * NP * DH;
  const bool useA = ((lane & 3) < 2);
  const bool odd  = (lane & 1);
  const int  ev   = lane & ~1;
  float acc = 0.f;

  #define ACCSTEP(V2, A4) {                                                   \
    const float vm  = odd ? (V2).y :  (V2).x;                                 \
    const float dsc = odd ? (V2).x : -(V2).y;                                 \
    acc += vm  * (useA ? (A4).x : (A4).z)                                     \
         + dsc * (useA ? (A4).y : (A4).w); }

  int j = 0;
  float2 v0, v1, v2, v3;
  if (kk >= 4) {
    const int a0 = msel[wid][0], a1 = msel[wid][1];
    const int a2 = msel[wid][2], a3 = msel[wid][3];
    v0 = *(const float2*)(vbase + (size_t)a0 * DH + ev);
    v1 = *(const float2*)(vbase + (size_t)a1 * DH + ev);
    v2 = *(const float2*)(vbase + (size_t)a2 * DH + ev);
    v3 = *(const float2*)(vbase + (size_t)a3 * DH + ev);
  }
  for (; j + 8 <= kk; j += 4) {
    const int n0 = msel[wid][j+4], n1 = msel[wid][j+5];
    const int n2 = msel[wid][j+6], n3 = msel[wid][j+7];
    const float2 w0 = *(const float2*)(vbase + (size_t)n0 * DH + ev);
    const float2 w1 = *(const float2*)(vbase + (size_t)n1 * DH + ev);
    const float2 w2 = *(const float2*)(vbase + (size_t)n2 * DH + ev);
    const float2 w3 = *(const float2*)(vbase + (size_t)n3 * DH + ev);
    const float4 A0 = ang[wid][j],   A1 = ang[wid][j+1];
    const float4 A2 = ang[wid][j+2], A3 = ang[wid][j+3];
    ACCSTEP(v0, A0); ACCSTEP(v1, A1); ACCSTEP(v2, A2); ACCSTEP(v3, A3);
    v0 = w0; v1 = w1; v2 = w2; v3 = w3;
  }
  if (j + 4 <= kk) {
    const float4 A0 = ang[wid][j],   A1 = ang[wid][j+1];
    const float4 A2 = ang[wid][j+2], A3 = ang[wid][j+3];
    ACCSTEP(v0, A0); ACCSTEP(v1, A1); ACCSTEP(v2, A2); ACCSTEP(v3, A3);
    j += 4;
  }
  for (; j < kk; ++j) {
    const int m = msel[wid][j];
    const float2 vv = *(const float2*)(vbase + (size_t)m * DH + ev);
    const float4 A  = ang[wid][j];
    ACCSTEP(vv, A);
  }
  #undef ACCSTEP

  otile[wid][lane] = acc;
  __syncthreads();
  if (wid == 0) {
    float4 o4;
    o4.x = otile[0][lane]; o4.y = otile[1][lane];
    o4.z = otile[2][lane]; o4.w = otile[3][lane];
    const int c = (lane << 2) | h;
    const int n0 = (rb * 4) & (NP - 1);
    *(float4*)&O[((size_t)b * DM + c) * NP + n0] = o4;
  }
}

// ---------------------------------------------------------------------------
// Kernel 4: final projection partials, split-K x4. 256 blocks. No bias.
// ---------------------------------------------------------------------------
__global__ __launch_bounds__(256) void final_part_kernel(
    const float* __restrict__ O, const float* __restrict__ Wm,
    float* __restrict__ Pf)
{
  const int tile = blockIdx.x;          // 16 = 4x4 of 64x64
  const int ks   = blockIdx.y;          // 4 K-slices of 64
  const int b    = blockIdx.z;
  const int tc = (tile >> 2) * 64;
  const int tp = (tile & 3) * 64;
  const float* X = O + (size_t)b * DM * NP;
  float* P = Pf + (size_t)ks * (DM * NP * 4) + (size_t)b * DM * NP;

  __shared__ float Ws[2][32][64];
  __shared__ float Xs[2][32][64];
  const int tid = threadIdx.x;
  const int ty = tid >> 4, tx = tid & 15;
  const int c0 = tid >> 3;
  const int k4 = tid & 7;
  const int pX = tid & 15;
  const int kX = tid >> 4;
  const int kbase = ks * 64;

  float4 wA, wB, xA, xB;
  #define LOADF(K0)                                                            \
    wA = *(const float4*)&Wm[(size_t)(tc + c0)      * DM + (K0) + k4 * 4];     \
    wB = *(const float4*)&Wm[(size_t)(tc + c0 + 32) * DM + (K0) + k4 * 4];     \
    xA = *(const float4*)&X[(size_t)((K0) + kX)      * NP + tp + pX * 4];      \
    xB = *(const float4*)&X[(size_t)((K0) + kX + 16) * NP + tp + pX * 4];

  #define STOREF(BUF)                                                          \
    Ws[BUF][k4*4+0][c0] = wA.x; Ws[BUF][k4*4+1][c0] = wA.y;                    \
    Ws[BUF][k4*4+2][c0] = wA.z; Ws[BUF][k4*4+3][c0] = wA.w;                    \
    Ws[BUF][k4*4+0][c0+32] = wB.x; Ws[BUF][k4*4+1][c0+32] = wB.y;              \
    Ws[BUF][k4*4+2][c0+32] = wB.z; Ws[BUF][k4*4+3][c0+32] = wB.w;              \
    *(float4*)&Xs[BUF][kX][pX*4]      = xA;                                    \
    *(float4*)&Xs[BUF][kX+16][pX*4]   = xB;

  LOADF(kbase);
  STOREF(0);
  __syncthreads();

  float acc[4][4];
  #pragma unroll
  for (int i = 0; i < 4; ++i)
    #pragma unroll
    for (int j = 0; j < 4; ++j) acc[i][j] = 0.f;

  for (int ch = 0; ch < 2; ++ch) {          // K = 64 per block
    const int cur = ch & 1;
    if (ch < 1) { LOADF(kbase + 32); }
    #pragma unroll
    for (int kk = 0; kk < 32; ++kk) {
      float4 a = *(const float4*)&Ws[cur][kk][ty * 4];
      float4 xv = *(const float4*)&Xs[cur][kk][tx * 4];
      float av[4] = {a.x, a.y, a.z, a.w};
      float xvv[4] = {xv.x, xv.y, xv.z, xv.w};
      #pragma unroll
      for (int i = 0; i < 4; ++i)
        #pragma unroll
        for (int j = 0; j < 4; ++j) acc[i][j] += av[i] * xvv[j];
    }
    if (ch < 1) {
      STOREF(cur ^ 1);
      __syncthreads();
    }
  }

  #pragma unroll
  for (int i = 0; i < 4; ++i) {
    float4 o4;
    o4.x = acc[i][0]; o4.y = acc[i][1]; o4.z = acc[i][2]; o4.w = acc[i][3];
    *(float4*)&P[(size_t)(tc + ty * 4 + i) * NP + tp + tx * 4] = o4;
  }
  #undef LOADF
  #undef STOREF
}

// ---------------------------------------------------------------------------
// Kernel 5: merge final partials + bias -> out. Pure streaming, coalesced.
// ---------------------------------------------------------------------------
__global__ __launch_bounds__(256) void final_merge_kernel(
    const float* __restrict__ Pf, const float* __restrict__ bm,
    float* __restrict__ out)
{
  const int u = blockIdx.x * 256 + threadIdx.x;   // 65536 float4 units
  const int c = (u >> 6) & 255;
  const float bb = bm[c];
  const size_t stride = (size_t)DM * NP * 4 / 4;  // in float4s: 262144/4
  const float4* P4 = (const float4*)Pf;
  float4 a = P4[u];
  float4 b2 = P4[u + stride];
  float4 c2 = P4[u + 2 * stride];
  float4 d2 = P4[u + 3 * stride];
  float4 o;
  o.x = a.x + b2.x + c2.x + d2.x + bb;
  o.y = a.y + b2.y + c2.y + d2.y + bb;
  o.z = a.z + b2.z + c2.z + d2.z + bb;
  o.w = a.w + b2.w + c2.w + d2.w + bb;
  ((float4*)out)[u] = o;
}

// ---------------------------------------------------------------------------
extern "C" void kernel_launch(void* const* d_in, const int* in_sizes, int n_in,
                              void* d_out, int out_size, void* d_ws, size_t ws_size,
                              hipStream_t stream)
{
  const float* x       = (const float*)d_in[0];
  const float* source  = (const float*)d_in[1];
  const float* x_pos   = (const float*)d_in[2];
  const float* src_pos = (const float*)d_in[3];
  const float* lrf     = (const float*)d_in[4];
  const float* Wq = (const float*)d_in[5];
  const float* bq = (const float*)d_in[6];
  const float* Wk = (const float*)d_in[7];
  const float* bk = (const float*)d_in[8];
  const float* Wv = (const float*)d_in[9];
  const float* bv = (const float*)d_in[10];
  const float* Wm = (const float*)d_in[11];
  const float* bm = (const float*)d_in[12];
  const int* kptr = (const int*)d_in[13];
  float* out = (float*)d_out;

  // workspace layout (floats)
  float* ws = (float*)d_ws;
  float* Ppart  = ws;                     // [2ks][3mat][4b][256][256] = 1572864
  float* scores = Ppart + 1572864;        // [16][256][256] = 1048576
  float* Vt     = scores + 1048576;       // [16][256][64]  = 262144
  float* O      = Vt + 262144;            // [4][256][256]  = 262144
  float* Pf     = O + 262144;             // [4ks][4b][256][256] = 1048576
  // total ~16 MB

  qkv_part_kernel<<<dim3(16, 3, 8), 256, 0, stream>>>(
      x, source, Wq, Wk, Wv, Ppart);
  score_gemm_kernel<<<dim3(16, 16), 256, 0, stream>>>(
      Ppart, bq, bk, bv, scores, Vt);
  attn_topk_kernel<<<dim3(1024), 256, 0, stream>>>(
      scores, Vt, x_pos, src_pos, lrf, kptr, O);
  final_part_kernel<<<dim3(16, 4, 4), 256, 0, stream>>>(
      O, Wm, Pf);
  final_merge_kernel<<<dim3(256), 256, 0, stream>>>(
      Pf, bm, out);
}